// Round 3
// baseline (3332.837 us; speedup 1.0000x reference)
//
#include <hip/hip_runtime.h>
#include <hip/hip_fp16.h>

// GRU scan, T=1024 B=128 H=256.
// Design:
//  - xproj = ins@Wi+bi via f16 MFMA GEMM (131072x256 @ 256x768), stored f16 in ws.
//  - recurrence: 1 workgroup per batch element (128 WGs), 256 threads; each thread
//    owns output element e and holds Wh columns {e, 256+e, 512+e} as f16 in 384 VGPRs
//    for the whole 1024-step loop. h broadcast per step via LDS (f16), dots via
//    v_dot2_f32_f16 (fp32 accum). Carry h kept fp32 in registers.
//  - resets dtype (bool-as-?) detected at runtime by a probe kernel.

typedef _Float16 hf2 __attribute__((ext_vector_type(2)));
typedef _Float16 f16x8 __attribute__((ext_vector_type(8)));
typedef float f32x4 __attribute__((ext_vector_type(4)));

static __device__ __forceinline__ hf2 bc_h2(unsigned u) {
  return __builtin_bit_cast(hf2, u);
}

static __device__ __forceinline__ unsigned pkrtz(float x, float y) {
  return __builtin_bit_cast(unsigned, __builtin_amdgcn_cvt_pkrtz(x, y));
}

static __device__ __forceinline__ float fdot2f(hf2 a, hf2 b, float c) {
  return __builtin_amdgcn_fdot2(a, b, c, false);
}

// ---------------------------------------------------------------- detector
// Distinguish how the bool `resets` array landed on device:
// mode 0: int32 0/1; mode 1: packed bytes; mode 2: float32.
__global__ void detect_mode(const unsigned* __restrict__ r, int nwords,
                            int* __restrict__ flags) {
  __shared__ int sf, sg;
  if (threadIdx.x == 0) { sf = 0; sg = 0; }
  __syncthreads();
  int f = 0, g = 0;
  for (int i = threadIdx.x; i < nwords; i += 256) {
    unsigned w = r[i];
    if (w == 0x3f800000u) f = 1;
    else if (w > 1u) g = 1;
  }
  if (f) atomicOr(&sf, 1);
  if (g) atomicOr(&sg, 1);
  __syncthreads();
  if (threadIdx.x == 0) flags[0] = sf ? 2 : (sg ? 1 : 0);
}

// ------------------------------------------------------------ weight prep
// WiT/WhT: [768][256] f16 transposes of the [256][768] fp32 weights.
__global__ void prep_weights(const float* __restrict__ Wi,
                             const float* __restrict__ Wh,
                             _Float16* __restrict__ WiT,
                             _Float16* __restrict__ WhT) {
  int j = blockIdx.x, k = threadIdx.x;
  if (j < 768) WiT[j * 256 + k] = (_Float16)Wi[k * 768 + j];
  else { j -= 768; WhT[j * 256 + k] = (_Float16)Wh[k * 768 + j]; }
}

// ------------------------------------------------------------------ GEMM
// C[M,768] (f16) = A[M,256] (fp32, cast f16) @ BT[768,256]^T + bias.
// 128x128 tile, BK=64, 4 waves (2x2), wave tile 64x64, mfma 16x16x32 f16.
#define LDK 72  // padded LDS row stride in halves

__global__ __launch_bounds__(256) void gemm_xproj(
    const float* __restrict__ A, const _Float16* __restrict__ BT,
    const float* __restrict__ bias, _Float16* __restrict__ C) {
  __shared__ _Float16 As[128 * LDK];
  __shared__ _Float16 Bs[128 * LDK];
  const int tid = threadIdx.x;
  const int lane = tid & 63, wid = tid >> 6;
  const int wr = (wid >> 1) * 64, wc = (wid & 1) * 64;
  const int bm = blockIdx.x, bn = blockIdx.y;
  f32x4 acc[4][4] = {};
  const int arow = tid >> 4;         // 0..15
  const int acol = (tid & 15) * 4;   // fp32 col in [0,64)
  const int brow = tid >> 3;         // 0..31
  const int bcol = (tid & 7) * 8;    // f16 col in [0,64)

  for (int kt = 0; kt < 4; ++kt) {
#pragma unroll
    for (int p = 0; p < 8; ++p) {  // stage A (fp32 -> f16)
      int row = arow + p * 16;
      float4 v = *(const float4*)(A + (size_t)(bm * 128 + row) * 256 + kt * 64 + acol);
      uint2 u;
      u.x = pkrtz(v.x, v.y);
      u.y = pkrtz(v.z, v.w);
      *(uint2*)(As + row * LDK + acol) = u;
    }
#pragma unroll
    for (int p = 0; p < 4; ++p) {  // stage B (already f16, row-contig k)
      int row = brow + p * 32;
      uint4 v = *(const uint4*)(BT + (size_t)(bn * 128 + row) * 256 + kt * 64 + bcol);
      *(uint4*)(Bs + row * LDK + bcol) = v;
    }
    __syncthreads();
#pragma unroll
    for (int ks = 0; ks < 2; ++ks) {
      f16x8 af[4], bf[4];
#pragma unroll
      for (int m = 0; m < 4; ++m)
        af[m] = *(const f16x8*)(As + (wr + m * 16 + (lane & 15)) * LDK + ks * 32 + (lane >> 4) * 8);
#pragma unroll
      for (int n = 0; n < 4; ++n)
        bf[n] = *(const f16x8*)(Bs + (wc + n * 16 + (lane & 15)) * LDK + ks * 32 + (lane >> 4) * 8);
#pragma unroll
      for (int m = 0; m < 4; ++m)
#pragma unroll
        for (int n = 0; n < 4; ++n)
          acc[m][n] = __builtin_amdgcn_mfma_f32_16x16x32_f16(af[m], bf[n], acc[m][n], 0, 0, 0);
    }
    __syncthreads();
  }
  // epilogue: C/D layout col=lane&15, row=(lane>>4)*4+j
  const int r0 = (lane >> 4) * 4;
  const int c0 = lane & 15;
#pragma unroll
  for (int n = 0; n < 4; ++n) {
    int col = bn * 128 + wc + n * 16 + c0;
    float bv = bias[col];
#pragma unroll
    for (int m = 0; m < 4; ++m) {
      int grow = bm * 128 + wr + m * 16 + r0;
#pragma unroll
      for (int j = 0; j < 4; ++j)
        C[(size_t)(grow + j) * 768 + col] = (_Float16)(acc[m][n][j] + bv);
    }
  }
}

// ------------------------------------------------------------------ scan
__global__ __launch_bounds__(256, 1) void gru_scan(
    const unsigned short* __restrict__ xp,  // [tc*128*768] f16 bits
    const void* __restrict__ resets, const uint4* __restrict__ WhT4,
    const float* __restrict__ bhn, const float* __restrict__ h0,
    float* __restrict__ hws, float* __restrict__ outF,
    float* __restrict__ outY, const int* __restrict__ flags, int t0, int tc,
    int isFirst, int isLast) {
  __shared__ alignas(16) _Float16 hL[256];
  const int b = blockIdx.x, e = threadIdx.x;
  const int mode = flags[0];
  const int* ri = (const int*)resets;
  const unsigned char* ru = (const unsigned char*)resets;
  const float* rf = (const float*)resets;

  // persistent recurrent weights: columns e (r), 256+e (z), 512+e (n)
  uint4 wr_[32], wz_[32], wn_[32];
  {
    const uint4* p0 = WhT4 + (size_t)e * 32;
    const uint4* p1 = WhT4 + (size_t)(e + 256) * 32;
    const uint4* p2 = WhT4 + (size_t)(e + 512) * 32;
#pragma unroll
    for (int c = 0; c < 32; ++c) { wr_[c] = p0[c]; wz_[c] = p1[c]; wn_[c] = p2[c]; }
  }
  const float bh = bhn[e];
  float hp = isFirst ? h0[b * 256 + e] : hws[b * 256 + e];
  bool rs = (mode == 0) ? (ri[t0 * 128 + b] != 0)
            : (mode == 1) ? (ru[t0 * 128 + b] != 0)
                          : (rf[t0 * 128 + b] != 0.f);
  float hu = rs ? 0.f : hp;  // h used by this step (post-reset), fp32 carry
  hL[e] = (_Float16)hu;
  __syncthreads();

  for (int tl = 0; tl < tc; ++tl) {
    const int t = t0 + tl;
    const unsigned short* xt = xp + ((size_t)tl * 128 + b) * 768;
    float xr = (float)__builtin_bit_cast(_Float16, xt[e]);
    float xz = (float)__builtin_bit_cast(_Float16, xt[256 + e]);
    float xn = (float)__builtin_bit_cast(_Float16, xt[512 + e]);

    float a0 = 0.f, a1 = 0.f, b0 = 0.f, b1 = 0.f, c0 = 0.f, c1 = 0.f;
    const uint4* hv = (const uint4*)hL;
#pragma unroll
    for (int c = 0; c < 32; ++c) {
      uint4 h4 = hv[c];  // wave-uniform broadcast read, 8 halves
      uint4 w0 = wr_[c], w1 = wz_[c], w2 = wn_[c];
      a0 = fdot2f(bc_h2(h4.x), bc_h2(w0.x), a0);
      b0 = fdot2f(bc_h2(h4.x), bc_h2(w1.x), b0);
      c0 = fdot2f(bc_h2(h4.x), bc_h2(w2.x), c0);
      a1 = fdot2f(bc_h2(h4.y), bc_h2(w0.y), a1);
      b1 = fdot2f(bc_h2(h4.y), bc_h2(w1.y), b1);
      c1 = fdot2f(bc_h2(h4.y), bc_h2(w2.y), c1);
      a0 = fdot2f(bc_h2(h4.z), bc_h2(w0.z), a0);
      b0 = fdot2f(bc_h2(h4.z), bc_h2(w1.z), b0);
      c0 = fdot2f(bc_h2(h4.z), bc_h2(w2.z), c0);
      a1 = fdot2f(bc_h2(h4.w), bc_h2(w0.w), a1);
      b1 = fdot2f(bc_h2(h4.w), bc_h2(w1.w), b1);
      c1 = fdot2f(bc_h2(h4.w), bc_h2(w2.w), c1);
    }
    float hr = a0 + a1, hz = b0 + b1, hn = c0 + c1;
    float r = 1.f / (1.f + __expf(-(xr + hr)));
    float z = 1.f / (1.f + __expf(-(xz + hz)));
    float xnn = xn + r * (hn + bh);
    xnn = fminf(15.f, fmaxf(-15.f, xnn));
    float ex = __expf(-2.f * xnn);
    float nv = (1.f - ex) / (1.f + ex);  // tanh
    float nh = (1.f - z) * nv + z * hu;

    outY[((size_t)t * 128 + b) * 256 + e] = nh;
    if (tl == tc - 1) {
      hws[b * 256 + e] = nh;
      if (isLast) outF[b * 256 + e] = nh;
    } else {
      const int tn = t + 1;
      bool r2 = (mode == 0) ? (ri[tn * 128 + b] != 0)
                : (mode == 1) ? (ru[tn * 128 + b] != 0)
                              : (rf[tn * 128 + b] != 0.f);
      hu = r2 ? 0.f : nh;
      __syncthreads();  // all dot-readers done with hL
      hL[e] = (_Float16)hu;
      __syncthreads();
    }
  }
}

// ---------------------------------------------------------------- launcher
extern "C" void kernel_launch(void* const* d_in, const int* in_sizes, int n_in,
                              void* d_out, int out_size, void* d_ws,
                              size_t ws_size, hipStream_t stream) {
  const float* ins = (const float*)d_in[0];
  const void* rsts = d_in[1];
  const float* Wi = (const float*)d_in[2];
  const float* bi = (const float*)d_in[3];
  const float* Wh = (const float*)d_in[4];
  const float* bhn = (const float*)d_in[5];
  const float* h0 = (const float*)d_in[6];
  float* outF = (float*)d_out;
  float* outY = outF + 128 * 256;

  char* w = (char*)d_ws;
  int* flags = (int*)w;                                   // @0
  _Float16* WiT = (_Float16*)(w + 256);                   // 768*256 f16
  _Float16* WhT = WiT + 768 * 256;                        // 768*256 f16
  float* hws = (float*)(WhT + 768 * 256);                 // 128*256 fp32
  unsigned short* xpb = (unsigned short*)(hws + 128 * 256);  // chunked xproj f16

  const size_t fixed = 256 + 2 * (size_t)768 * 256 * 2 + (size_t)128 * 256 * 4;
  const size_t per_t = (size_t)128 * 768 * 2;
  size_t avail = ws_size > fixed ? ws_size - fixed : 0;
  int Tc = (int)(avail / per_t);
  if (Tc > 1024) Tc = 1024;
  if (Tc < 1) Tc = 1;

  detect_mode<<<1, 256, 0, stream>>>((const unsigned*)rsts, 1024 * 128 / 4, flags);
  prep_weights<<<1536, 256, 0, stream>>>(Wi, Wh, WiT, WhT);

  for (int t0 = 0; t0 < 1024; t0 += Tc) {
    int tc = (1024 - t0) < Tc ? (1024 - t0) : Tc;
    gemm_xproj<<<dim3(tc, 6), 256, 0, stream>>>(
        ins + (size_t)t0 * 128 * 256, WiT, bi, (_Float16*)xpb);
    gru_scan<<<128, 256, 0, stream>>>(
        xpb, rsts, (const uint4*)WhT, bhn, h0, hws, outF, outY, flags, t0, tc,
        t0 == 0 ? 1 : 0, (t0 + tc == 1024) ? 1 : 0);
  }
}

// Round 4
// 1611.719 us; speedup vs baseline: 2.0679x; 2.0679x over previous
//
#include <hip/hip_runtime.h>
#include <hip/hip_fp16.h>

// GRU scan, T=1024 B=128 H=256.
//  - xproj = ins@Wi+bi via f16 MFMA GEMM, stored f16 in ws.
//  - recurrence: 1 WG per batch element (128 WGs), 512 threads (8 waves, 2/SIMD).
//    Thread (e, half) owns k-range [half*128,+128) of Wh columns {e,256+e,512+e}
//    as f16 in 192 VGPRs (fits 256-arch-VGPR cap -> stays resident; the r3 version
//    needed 384 and was demoted to per-step L2 reloads = 7000 cyc/step).
//    h broadcast per step via LDS f16; v_dot2_f32_f16 fp32 accum; cross-half
//    reduce via LDS; fp32 carry in half-0 registers; resets preloaded to LDS.

typedef _Float16 hf2 __attribute__((ext_vector_type(2)));
typedef _Float16 f16x8 __attribute__((ext_vector_type(8)));
typedef float f32x4 __attribute__((ext_vector_type(4)));

static __device__ __forceinline__ hf2 bc_h2(unsigned u) {
  return __builtin_bit_cast(hf2, u);
}

static __device__ __forceinline__ unsigned pkrtz(float x, float y) {
  return __builtin_bit_cast(unsigned, __builtin_amdgcn_cvt_pkrtz(x, y));
}

static __device__ __forceinline__ float fdot2f(hf2 a, hf2 b, float c) {
  return __builtin_amdgcn_fdot2(a, b, c, false);
}

// ---------------------------------------------------------------- detector
// mode 0: int32 0/1; mode 1: packed bytes; mode 2: float32.
__global__ void detect_mode(const unsigned* __restrict__ r, int nwords,
                            int* __restrict__ flags) {
  __shared__ int sf, sg;
  if (threadIdx.x == 0) { sf = 0; sg = 0; }
  __syncthreads();
  int f = 0, g = 0;
  for (int i = threadIdx.x; i < nwords; i += 256) {
    unsigned w = r[i];
    if (w == 0x3f800000u) f = 1;
    else if (w > 1u) g = 1;
  }
  if (f) atomicOr(&sf, 1);
  if (g) atomicOr(&sg, 1);
  __syncthreads();
  if (threadIdx.x == 0) flags[0] = sf ? 2 : (sg ? 1 : 0);
}

// ------------------------------------------------------------ weight prep
__global__ void prep_weights(const float* __restrict__ Wi,
                             const float* __restrict__ Wh,
                             _Float16* __restrict__ WiT,
                             _Float16* __restrict__ WhT) {
  int j = blockIdx.x, k = threadIdx.x;
  if (j < 768) WiT[j * 256 + k] = (_Float16)Wi[k * 768 + j];
  else { j -= 768; WhT[j * 256 + k] = (_Float16)Wh[k * 768 + j]; }
}

// ------------------------------------------------------------------ GEMM
// C[M,768] (f16) = A[M,256] (fp32->f16) @ BT[768,256]^T + bias.
#define LDK 72

__global__ __launch_bounds__(256) void gemm_xproj(
    const float* __restrict__ A, const _Float16* __restrict__ BT,
    const float* __restrict__ bias, _Float16* __restrict__ C) {
  __shared__ _Float16 As[128 * LDK];
  __shared__ _Float16 Bs[128 * LDK];
  const int tid = threadIdx.x;
  const int lane = tid & 63, wid = tid >> 6;
  const int wr = (wid >> 1) * 64, wc = (wid & 1) * 64;
  const int bm = blockIdx.x, bn = blockIdx.y;
  f32x4 acc[4][4] = {};
  const int arow = tid >> 4;
  const int acol = (tid & 15) * 4;
  const int brow = tid >> 3;
  const int bcol = (tid & 7) * 8;

  for (int kt = 0; kt < 4; ++kt) {
#pragma unroll
    for (int p = 0; p < 8; ++p) {
      int row = arow + p * 16;
      float4 v = *(const float4*)(A + (size_t)(bm * 128 + row) * 256 + kt * 64 + acol);
      uint2 u;
      u.x = pkrtz(v.x, v.y);
      u.y = pkrtz(v.z, v.w);
      *(uint2*)(As + row * LDK + acol) = u;
    }
#pragma unroll
    for (int p = 0; p < 4; ++p) {
      int row = brow + p * 32;
      uint4 v = *(const uint4*)(BT + (size_t)(bn * 128 + row) * 256 + kt * 64 + bcol);
      *(uint4*)(Bs + row * LDK + bcol) = v;
    }
    __syncthreads();
#pragma unroll
    for (int ks = 0; ks < 2; ++ks) {
      f16x8 af[4], bf[4];
#pragma unroll
      for (int m = 0; m < 4; ++m)
        af[m] = *(const f16x8*)(As + (wr + m * 16 + (lane & 15)) * LDK + ks * 32 + (lane >> 4) * 8);
#pragma unroll
      for (int n = 0; n < 4; ++n)
        bf[n] = *(const f16x8*)(Bs + (wc + n * 16 + (lane & 15)) * LDK + ks * 32 + (lane >> 4) * 8);
#pragma unroll
      for (int m = 0; m < 4; ++m)
#pragma unroll
        for (int n = 0; n < 4; ++n)
          acc[m][n] = __builtin_amdgcn_mfma_f32_16x16x32_f16(af[m], bf[n], acc[m][n], 0, 0, 0);
    }
    __syncthreads();
  }
  const int r0 = (lane >> 4) * 4;
  const int c0 = lane & 15;
#pragma unroll
  for (int n = 0; n < 4; ++n) {
    int col = bn * 128 + wc + n * 16 + c0;
    float bv = bias[col];
#pragma unroll
    for (int m = 0; m < 4; ++m) {
      int grow = bm * 128 + wr + m * 16 + r0;
#pragma unroll
      for (int j = 0; j < 4; ++j)
        C[(size_t)(grow + j) * 768 + col] = (_Float16)(acc[m][n][j] + bv);
    }
  }
}

// ------------------------------------------------------------------ scan
__global__ __launch_bounds__(512, 1) void gru_scan(
    const unsigned short* __restrict__ xp,  // [tc*128*768] f16 bits
    const void* __restrict__ resets, const uint4* __restrict__ WhT4,
    const float* __restrict__ bhn, const float* __restrict__ h0,
    float* __restrict__ hws, float* __restrict__ outF,
    float* __restrict__ outY, const int* __restrict__ flags, int t0, int tc,
    int isFirst, int isLast) {
  __shared__ alignas(16) _Float16 hL[256];
  __shared__ float pS[3][256];
  __shared__ unsigned char rl[1024];
  const int b = blockIdx.x;
  const int tid = threadIdx.x;
  const int e = tid & 255;
  const int half = tid >> 8;  // wave-uniform (waves 0-3 vs 4-7)

  // preload reset flags for this chunk into LDS (mode-normalized to bytes)
  {
    const int mode = flags[0];
    const int* ri = (const int*)resets;
    const unsigned char* ru = (const unsigned char*)resets;
    const float* rf = (const float*)resets;
    for (int i = tid; i < tc; i += 512) {
      int t = t0 + i;
      bool r = (mode == 0) ? (ri[t * 128 + b] != 0)
               : (mode == 1) ? (ru[t * 128 + b] != 0)
                             : (rf[t * 128 + b] != 0.f);
      rl[i] = r ? 1 : 0;
    }
  }

  // persistent weights: 16 uint4 per gate column over k-range [half*128,+128)
  uint4 wr_[16], wz_[16], wn_[16];
  {
    const uint4* p0 = WhT4 + (size_t)e * 32 + half * 16;
    const uint4* p1 = WhT4 + (size_t)(e + 256) * 32 + half * 16;
    const uint4* p2 = WhT4 + (size_t)(e + 512) * 32 + half * 16;
#pragma unroll
    for (int c = 0; c < 16; ++c) { wr_[c] = p0[c]; wz_[c] = p1[c]; wn_[c] = p2[c]; }
  }
  const float bh = bhn[e];
  float hp = 0.f;
  if (half == 0) hp = isFirst ? h0[b * 256 + e] : hws[b * 256 + e];
  __syncthreads();  // rl visible
  float hu = 0.f;
  if (half == 0) {
    hu = rl[0] ? 0.f : hp;
    hL[e] = (_Float16)hu;
  }
  __syncthreads();  // hL visible

  for (int tl = 0; tl < tc; ++tl) {
    const unsigned short* xt = xp + ((size_t)tl * 128 + b) * 768;
    float xr = 0.f, xz = 0.f, xn = 0.f;
    if (half == 0) {  // issued early; used after ~770 cyc of dots
      xr = (float)__builtin_bit_cast(_Float16, xt[e]);
      xz = (float)__builtin_bit_cast(_Float16, xt[256 + e]);
      xn = (float)__builtin_bit_cast(_Float16, xt[512 + e]);
    }

    float a0 = 0.f, a1 = 0.f, b0 = 0.f, b1 = 0.f, c0 = 0.f, c1 = 0.f;
    const uint4* hv = (const uint4*)hL + half * 16;
#pragma unroll
    for (int c = 0; c < 16; ++c) {
      uint4 h4 = hv[c];  // wave-uniform broadcast read
      uint4 w0 = wr_[c], w1 = wz_[c], w2 = wn_[c];
      a0 = fdot2f(bc_h2(h4.x), bc_h2(w0.x), a0);
      b0 = fdot2f(bc_h2(h4.x), bc_h2(w1.x), b0);
      c0 = fdot2f(bc_h2(h4.x), bc_h2(w2.x), c0);
      a1 = fdot2f(bc_h2(h4.y), bc_h2(w0.y), a1);
      b1 = fdot2f(bc_h2(h4.y), bc_h2(w1.y), b1);
      c1 = fdot2f(bc_h2(h4.y), bc_h2(w2.y), c1);
      a0 = fdot2f(bc_h2(h4.z), bc_h2(w0.z), a0);
      b0 = fdot2f(bc_h2(h4.z), bc_h2(w1.z), b0);
      c0 = fdot2f(bc_h2(h4.z), bc_h2(w2.z), c0);
      a1 = fdot2f(bc_h2(h4.w), bc_h2(w0.w), a1);
      b1 = fdot2f(bc_h2(h4.w), bc_h2(w1.w), b1);
      c1 = fdot2f(bc_h2(h4.w), bc_h2(w2.w), c1);
    }
    float hr = a0 + a1, hz = b0 + b1, hn = c0 + c1;
    if (half) { pS[0][e] = hr; pS[1][e] = hz; pS[2][e] = hn; }
    __syncthreads();  // partials visible; all hL reads done
    if (half == 0) {
      hr += pS[0][e]; hz += pS[1][e]; hn += pS[2][e];
      float r = 1.f / (1.f + __expf(-(xr + hr)));
      float z = 1.f / (1.f + __expf(-(xz + hz)));
      float xnn = xn + r * (hn + bh);
      xnn = fminf(15.f, fmaxf(-15.f, xnn));
      float ex = __expf(-2.f * xnn);
      float nv = (1.f - ex) / (1.f + ex);  // tanh
      float nh = (1.f - z) * nv + z * hu;

      outY[((size_t)(t0 + tl) * 128 + b) * 256 + e] = nh;
      if (tl == tc - 1) {
        hws[b * 256 + e] = nh;
        if (isLast) outF[b * 256 + e] = nh;
      } else {
        hu = rl[tl + 1] ? 0.f : nh;
        hL[e] = (_Float16)hu;
      }
    }
    __syncthreads();  // hL ready for next step
  }
}

// ---------------------------------------------------------------- launcher
extern "C" void kernel_launch(void* const* d_in, const int* in_sizes, int n_in,
                              void* d_out, int out_size, void* d_ws,
                              size_t ws_size, hipStream_t stream) {
  const float* ins = (const float*)d_in[0];
  const void* rsts = d_in[1];
  const float* Wi = (const float*)d_in[2];
  const float* bi = (const float*)d_in[3];
  const float* Wh = (const float*)d_in[4];
  const float* bhn = (const float*)d_in[5];
  const float* h0 = (const float*)d_in[6];
  float* outF = (float*)d_out;
  float* outY = outF + 128 * 256;

  char* w = (char*)d_ws;
  int* flags = (int*)w;                                   // @0
  _Float16* WiT = (_Float16*)(w + 256);                   // 768*256 f16
  _Float16* WhT = WiT + 768 * 256;                        // 768*256 f16
  float* hws = (float*)(WhT + 768 * 256);                 // 128*256 fp32
  unsigned short* xpb = (unsigned short*)(hws + 128 * 256);  // chunked xproj f16

  const size_t fixed = 256 + 2 * (size_t)768 * 256 * 2 + (size_t)128 * 256 * 4;
  const size_t per_t = (size_t)128 * 768 * 2;
  size_t avail = ws_size > fixed ? ws_size - fixed : 0;
  int Tc = (int)(avail / per_t);
  if (Tc > 1024) Tc = 1024;
  if (Tc < 1) Tc = 1;

  detect_mode<<<1, 256, 0, stream>>>((const unsigned*)rsts, 1024 * 128 / 4, flags);
  prep_weights<<<1536, 256, 0, stream>>>(Wi, Wh, WiT, WhT);

  for (int t0 = 0; t0 < 1024; t0 += Tc) {
    int tc = (1024 - t0) < Tc ? (1024 - t0) : Tc;
    gemm_xproj<<<dim3(tc, 6), 256, 0, stream>>>(
        ins + (size_t)t0 * 128 * 256, WiT, bi, (_Float16*)xpb);
    gru_scan<<<128, 512, 0, stream>>>(
        xpb, rsts, (const uint4*)WhT, bhn, h0, hws, outF, outY, flags, t0, tc,
        t0 == 0 ? 1 : 0, (t0 + tc == 1024) ? 1 : 0);
  }
}